// Round 2
// baseline (284.041 us; speedup 1.0000x reference)
//
#include <hip/hip_runtime.h>

#define NBINS 15

// One wave (64 lanes) per row of C=100 logits.
// ws layout: [0..15) counts, [15..30) conf sums, [30..45) acc sums (floats).
__global__ __launch_bounds__(256) void ece_main(
    const float* __restrict__ logits,
    const int* __restrict__ labels,   // harness pushes integer inputs as int32
    float* __restrict__ ws, int N, int C) {
  __shared__ float s_cnt[NBINS], s_conf[NBINS], s_acc[NBINS];
  const int tid = threadIdx.x;
  if (tid < NBINS) { s_cnt[tid] = 0.f; s_conf[tid] = 0.f; s_acc[tid] = 0.f; }
  __syncthreads();

  const int lane = tid & 63;
  const int wavesPerBlock = blockDim.x >> 6;
  const long long waveId = (long long)blockIdx.x * wavesPerBlock + (tid >> 6);
  const long long nWaves = (long long)gridDim.x * wavesPerBlock;
  const int tail = C - 64;  // 36 for C=100

  for (long long row = waveId; row < N; row += nWaves) {
    const float* rp = logits + row * (long long)C;
    float v0 = rp[lane];
    float v1 = (lane < tail) ? rp[64 + lane] : -INFINITY;

    // (max, argmax) with first-occurrence tie-break (lower index wins).
    float bv = v0; int bi = lane;
    if (v1 > bv) { bv = v1; bi = lane + 64; }   // v0 >= v1 keeps lower idx
    #pragma unroll
    for (int off = 32; off; off >>= 1) {
      float ov = __shfl_xor(bv, off);
      int   oi = __shfl_xor(bi, off);
      if (ov > bv || (ov == bv && oi < bi)) { bv = ov; bi = oi; }
    }

    // sum of exp(x - max); the max element contributes exp(0)=1.
    float s = __expf(v0 - bv);
    if (lane < tail) s += __expf(v1 - bv);
    #pragma unroll
    for (int off = 32; off; off >>= 1) s += __shfl_xor(s, off);

    if (lane == 0) {
      float conf = 1.0f / s;                       // softmax max prob
      int b = (int)ceilf(conf * (float)NBINS) - 1;
      b = b < 0 ? 0 : (b > NBINS - 1 ? NBINS - 1 : b);
      float acc = (bi == labels[row]) ? 1.0f : 0.0f;
      atomicAdd(&s_cnt[b], 1.0f);
      atomicAdd(&s_conf[b], conf);
      atomicAdd(&s_acc[b], acc);
    }
  }
  __syncthreads();
  if (tid < NBINS) {
    atomicAdd(&ws[tid],             s_cnt[tid]);
    atomicAdd(&ws[NBINS + tid],     s_conf[tid]);
    atomicAdd(&ws[2 * NBINS + tid], s_acc[tid]);
  }
}

__global__ void ece_final(const float* __restrict__ ws,
                          float* __restrict__ out, int N) {
  float ece = 0.f;
  #pragma unroll
  for (int b = 0; b < NBINS; ++b) {
    float c = ws[b];
    if (c > 0.f) {
      float d = fmaxf(c, 1.0f);
      float avg_conf = ws[NBINS + b] / d;
      float avg_acc  = ws[2 * NBINS + b] / d;
      ece += fabsf(avg_conf - avg_acc) * (c / (float)N);
    }
  }
  out[0] = ece;
}

extern "C" void kernel_launch(void* const* d_in, const int* in_sizes, int n_in,
                              void* d_out, int out_size, void* d_ws, size_t ws_size,
                              hipStream_t stream) {
  const float* logits = (const float*)d_in[0];
  const int* labels = (const int*)d_in[1];
  const int N = in_sizes[1];
  const int C = in_sizes[0] / in_sizes[1];
  float* ws = (float*)d_ws;
  float* out = (float*)d_out;

  hipMemsetAsync(ws, 0, 3 * NBINS * sizeof(float), stream);
  ece_main<<<2048, 256, 0, stream>>>(logits, labels, ws, N, C);
  ece_final<<<1, 1, 0, stream>>>(ws, out, N);
}

// Round 3
// 90.735 us; speedup vs baseline: 3.1304x; 3.1304x over previous
//
#include <hip/hip_runtime.h>

#define NBINS 15
#define ROWS 128          // rows per block (one chunk)
#define BLK 128           // threads per block (2 waves)
#define NC 100            // classes (fixed by the reference setup)
#define SEGS 50           // 1 KiB staging segments per chunk: 128*400/1024
#define NSLOT 32          // spread factor for global histogram atomics
#define SSTR 48           // slot stride in floats (>= 3*NBINS)

typedef __attribute__((address_space(3))) unsigned int lds_u32_t;
typedef const __attribute__((address_space(1))) unsigned int glob_u32_t;

__global__ __launch_bounds__(BLK) void ece_main(
    const float* __restrict__ logits,
    const int* __restrict__ labels,
    float* __restrict__ ws, int N) {
  __shared__ float smem[ROWS * NC];     // 51200 B, linear image of 128 rows
  __shared__ float s_hist[3 * NBINS];

  const int tid = threadIdx.x;
  const int lane = tid & 63;
  const int wv = tid >> 6;              // wave id in block: 0..1
  if (tid < 3 * NBINS) s_hist[tid] = 0.f;

  // ---- stage: linear chunk -> LDS via global_load_lds, 16 B per lane ----
  const size_t total_bytes = (size_t)N * NC * 4;           // 4e8, %1024 == 0
  const size_t chunk_byte = (size_t)blockIdx.x * (ROWS * NC * 4);
  #pragma unroll
  for (int k = 0; k < SEGS / 2; ++k) {
    const int seg = 2 * k + wv;
    const size_t gb = chunk_byte + (size_t)seg * 1024;
    if (gb < total_bytes) {            // wave-uniform (tail block skips segs)
      const char* g = (const char*)logits + gb + (size_t)lane * 16;
      float* l = smem + seg * 256;     // wave-uniform LDS base
      __builtin_amdgcn_global_load_lds((glob_u32_t*)g, (lds_u32_t*)l, 16, 0, 0);
    }
  }
  asm volatile("s_waitcnt vmcnt(0)" ::: "memory");
  __syncthreads();

  // ---- compute: one thread per row, no cross-lane ops ----
  const int row = blockIdx.x * ROWS + tid;
  if (row < N) {
    const float4* r4 = (const float4*)(smem + tid * NC);   // 400B stride, 16B aligned

    // argmax: 4 independent online chains (first occurrence kept within lane)
    float4 bv = r4[0];
    int bix = 0, biy = 1, biz = 2, biw = 3;
    #pragma unroll
    for (int j = 1; j < NC / 4; ++j) {
      float4 u = r4[j];
      if (u.x > bv.x) { bv.x = u.x; bix = 4 * j; }
      if (u.y > bv.y) { bv.y = u.y; biy = 4 * j + 1; }
      if (u.z > bv.z) { bv.z = u.z; biz = 4 * j + 2; }
      if (u.w > bv.w) { bv.w = u.w; biw = 4 * j + 3; }
    }
    // merge lanes with first-occurrence tie-break (smaller index wins ties)
    float m = bv.x; int mi = bix;
    if (bv.y > m || (bv.y == m && biy < mi)) { m = bv.y; mi = biy; }
    if (bv.z > m || (bv.z == m && biz < mi)) { m = bv.z; mi = biz; }
    if (bv.w > m || (bv.w == m && biw < mi)) { m = bv.w; mi = biw; }

    // exp-sum with 4 independent accumulators (re-read row from LDS)
    float sx = 0.f, sy = 0.f, sz = 0.f, sw = 0.f;
    #pragma unroll
    for (int j = 0; j < NC / 4; ++j) {
      float4 u = r4[j];
      sx += __expf(u.x - m);
      sy += __expf(u.y - m);
      sz += __expf(u.z - m);
      sw += __expf(u.w - m);
    }
    float conf = 1.0f / ((sx + sy) + (sz + sw));

    int b = (int)ceilf(conf * (float)NBINS) - 1;
    b = b < 0 ? 0 : (b > NBINS - 1 ? NBINS - 1 : b);
    float acc = (mi == labels[row]) ? 1.0f : 0.0f;
    atomicAdd(&s_hist[b], 1.0f);
    atomicAdd(&s_hist[NBINS + b], conf);
    atomicAdd(&s_hist[2 * NBINS + b], acc);
  }
  __syncthreads();

  if (tid < 3 * NBINS) {
    float v = s_hist[tid];
    if (v != 0.f)
      atomicAdd(&ws[(blockIdx.x & (NSLOT - 1)) * SSTR + tid], v);
  }
}

__global__ void ece_final(const float* __restrict__ ws,
                          float* __restrict__ out, int N) {
  __shared__ float per_bin[NBINS];
  const int b = threadIdx.x;
  if (b < NBINS) {
    float cnt = 0.f, cf = 0.f, ac = 0.f;
    #pragma unroll
    for (int s = 0; s < NSLOT; ++s) {
      cnt += ws[s * SSTR + b];
      cf  += ws[s * SSTR + NBINS + b];
      ac  += ws[s * SSTR + 2 * NBINS + b];
    }
    float d = fmaxf(cnt, 1.0f);
    per_bin[b] = (cnt > 0.f) ? fabsf(cf / d - ac / d) * (cnt / (float)N) : 0.f;
  }
  __syncthreads();
  if (b == 0) {
    float e = 0.f;
    #pragma unroll
    for (int i = 0; i < NBINS; ++i) e += per_bin[i];
    out[0] = e;
  }
}

extern "C" void kernel_launch(void* const* d_in, const int* in_sizes, int n_in,
                              void* d_out, int out_size, void* d_ws, size_t ws_size,
                              hipStream_t stream) {
  const float* logits = (const float*)d_in[0];
  const int* labels = (const int*)d_in[1];
  const int N = in_sizes[1];
  float* ws = (float*)d_ws;
  float* out = (float*)d_out;

  hipMemsetAsync(ws, 0, NSLOT * SSTR * sizeof(float), stream);
  const int grid = (N + ROWS - 1) / ROWS;
  ece_main<<<grid, BLK, 0, stream>>>(logits, labels, ws, N);
  ece_final<<<1, 64, 0, stream>>>(ws, out, N);
}

// Round 4
// 88.430 us; speedup vs baseline: 3.2121x; 1.0261x over previous
//
#include <hip/hip_runtime.h>

#define NBINS 15
#define RPC   64                  // rows per chunk == lanes (one row per lane)
#define SEGS  25                  // 1 KiB staging segments: 64*400/1024
#define BUF_FLTS (RPC * 100 + RPC)  // 6464 floats: 64 rows + 64 labels
#define NSLOT 32                  // spread factor for global histogram atomics
#define SSTR  48                  // slot stride in floats (>= 3*NBINS)
#define GRID  768                 // 256 CU x 3 blocks (LDS-limited occupancy)

typedef __attribute__((address_space(3))) unsigned int lds_u32_t;
typedef const __attribute__((address_space(1))) unsigned int glob_u32_t;

__device__ __forceinline__ void stage_chunk(const float* __restrict__ logits,
                                            const int* __restrict__ labels,
                                            long long chunk, float* lbase, int lane) {
  const char* gbase = (const char*)logits + chunk * (long long)(RPC * 100 * 4);
  #pragma unroll
  for (int seg = 0; seg < SEGS; ++seg) {
    const char* g = gbase + seg * 1024 + lane * 16;
    __builtin_amdgcn_global_load_lds((glob_u32_t*)g, (lds_u32_t*)(lbase + seg * 256),
                                     16, 0, 0);
  }
  const char* gl = (const char*)(labels + chunk * RPC + lane);
  __builtin_amdgcn_global_load_lds((glob_u32_t*)gl, (lds_u32_t*)(lbase + RPC * 100),
                                   4, 0, 0);
}

// Per-row math from 25 float4s; returns conf and argmax (first occurrence).
__device__ __forceinline__ void row_reduce(const float4* __restrict__ r4,
                                           float& conf, int& mi) {
  float4 bv = r4[0];
  int bix = 0, biy = 1, biz = 2, biw = 3;
  #pragma unroll
  for (int j = 1; j < 25; ++j) {
    float4 u = r4[j];
    if (u.x > bv.x) { bv.x = u.x; bix = 4 * j; }
    if (u.y > bv.y) { bv.y = u.y; biy = 4 * j + 1; }
    if (u.z > bv.z) { bv.z = u.z; biz = 4 * j + 2; }
    if (u.w > bv.w) { bv.w = u.w; biw = 4 * j + 3; }
  }
  float m = bv.x; mi = bix;
  if (bv.y > m || (bv.y == m && biy < mi)) { m = bv.y; mi = biy; }
  if (bv.z > m || (bv.z == m && biz < mi)) { m = bv.z; mi = biz; }
  if (bv.w > m || (bv.w == m && biw < mi)) { m = bv.w; mi = biw; }

  float sx = 0.f, sy = 0.f, sz = 0.f, sw = 0.f;
  #pragma unroll
  for (int j = 0; j < 25; ++j) {
    float4 u = r4[j];
    sx += __expf(u.x - m);
    sy += __expf(u.y - m);
    sz += __expf(u.z - m);
    sw += __expf(u.w - m);
  }
  conf = 1.0f / ((sx + sy) + (sz + sw));
}

__device__ __forceinline__ void bin_and_add(float conf, int mi, int lab,
                                            float* s_hist) {
  int b = (int)ceilf(conf * (float)NBINS) - 1;
  b = b < 0 ? 0 : (b > NBINS - 1 ? NBINS - 1 : b);
  atomicAdd(&s_hist[b], 1.0f);
  atomicAdd(&s_hist[NBINS + b], conf);
  atomicAdd(&s_hist[2 * NBINS + b], (mi == lab) ? 1.0f : 0.0f);
}

// Single-wave persistent blocks: no barriers; double-buffered LDS with
// counted vmcnt so prefetch loads stay in flight across compute (T3/T4).
__global__ __launch_bounds__(64) void ece_main(
    const float* __restrict__ logits, const int* __restrict__ labels,
    float* __restrict__ ws, int N) {
  __shared__ float smem[2 * BUF_FLTS];   // 51712 B
  __shared__ float s_hist[3 * NBINS];
  const int lane = threadIdx.x;
  if (lane < 3 * NBINS) s_hist[lane] = 0.f;   // single wave: ordered, no barrier

  const long long nfull = (long long)N / RPC;
  long long c = blockIdx.x;
  int cur = 0;
  if (c < nfull) stage_chunk(logits, labels, c, smem, lane);

  for (; c < nfull; c += gridDim.x) {
    const long long nx = c + gridDim.x;
    if (nx < nfull) {
      stage_chunk(logits, labels, nx, smem + (cur ^ 1) * BUF_FLTS, lane);
      // wait only for the PREVIOUS chunk's 26 loads; keep these 26 in flight
      asm volatile("s_waitcnt vmcnt(26)" ::: "memory");
    } else {
      asm volatile("s_waitcnt vmcnt(0)" ::: "memory");
    }
    const float* lbase = smem + cur * BUF_FLTS;
    float conf; int mi;
    row_reduce((const float4*)(lbase + lane * 100), conf, mi);
    const int lab = ((const int*)(lbase + RPC * 100))[lane];
    bin_and_add(conf, mi, lab, s_hist);
    cur ^= 1;
  }

  // tail rows (N % 64) — none for N=1e6, kept for generality
  const long long trow = nfull * RPC + lane;
  if (blockIdx.x == 0 && trow < N) {
    float conf; int mi;
    row_reduce((const float4*)(logits + trow * 100), conf, mi);
    bin_and_add(conf, mi, labels[trow], s_hist);
  }

  __syncthreads();
  if (lane < 3 * NBINS) {
    float v = s_hist[lane];
    if (v != 0.f)
      atomicAdd(&ws[(blockIdx.x & (NSLOT - 1)) * SSTR + lane], v);
  }
}

__global__ void ece_final(const float* __restrict__ ws,
                          float* __restrict__ out, int N) {
  __shared__ float per_bin[NBINS];
  const int b = threadIdx.x;
  if (b < NBINS) {
    float cnt = 0.f, cf = 0.f, ac = 0.f;
    #pragma unroll
    for (int s = 0; s < NSLOT; ++s) {
      cnt += ws[s * SSTR + b];
      cf  += ws[s * SSTR + NBINS + b];
      ac  += ws[s * SSTR + 2 * NBINS + b];
    }
    float d = fmaxf(cnt, 1.0f);
    per_bin[b] = (cnt > 0.f) ? fabsf(cf / d - ac / d) * (cnt / (float)N) : 0.f;
  }
  __syncthreads();
  if (b == 0) {
    float e = 0.f;
    #pragma unroll
    for (int i = 0; i < NBINS; ++i) e += per_bin[i];
    out[0] = e;
  }
}

extern "C" void kernel_launch(void* const* d_in, const int* in_sizes, int n_in,
                              void* d_out, int out_size, void* d_ws, size_t ws_size,
                              hipStream_t stream) {
  const float* logits = (const float*)d_in[0];
  const int* labels = (const int*)d_in[1];
  const int N = in_sizes[1];
  float* ws = (float*)d_ws;
  float* out = (float*)d_out;

  hipMemsetAsync(ws, 0, NSLOT * SSTR * sizeof(float), stream);
  ece_main<<<GRID, 64, 0, stream>>>(logits, labels, ws, N);
  ece_final<<<1, 64, 0, stream>>>(ws, out, N);
}